// Round 1
// baseline (956.572 us; speedup 1.0000x reference)
//
#include <hip/hip_runtime.h>
#include <math.h>

#define TT 5
#define HEADS 6
#define HD 32
#define DIM 192
#define NWIN 320              // tokens per window = T*8*8
#define LTOK (TT*64*64)       // 20480
#define BATCH 2
#define MROWS (BATCH*LTOK)    // 40960
#define QSCALE 0.17677669529663687f   // 1/sqrt(32)

// ---------------- LayerNorm: one wave (64 lanes) per token, 3 elems/lane ----
__global__ __launch_bounds__(256) void ln_kernel(
    const float* __restrict__ x, const float* __restrict__ g,
    const float* __restrict__ b, float* __restrict__ out)
{
    int tok  = blockIdx.x * 4 + (threadIdx.x >> 6);
    int lane = threadIdx.x & 63;
    const float* xr = x + (size_t)tok * DIM;
    float v0 = xr[lane], v1 = xr[lane + 64], v2 = xr[lane + 128];
    float s = v0 + v1 + v2;
    #pragma unroll
    for (int off = 32; off; off >>= 1) s += __shfl_xor(s, off, 64);
    float mu = s * (1.0f / 192.0f);
    float d0 = v0 - mu, d1 = v1 - mu, d2 = v2 - mu;
    float vs = d0 * d0 + d1 * d1 + d2 * d2;
    #pragma unroll
    for (int off = 32; off; off >>= 1) vs += __shfl_xor(vs, off, 64);
    float rstd = rsqrtf(vs * (1.0f / 192.0f) + 1e-5f);
    float* orow = out + (size_t)tok * DIM;
    orow[lane]       = d0 * rstd * g[lane]       + b[lane];
    orow[lane + 64]  = d1 * rstd * g[lane + 64]  + b[lane + 64];
    orow[lane + 128] = d2 * rstd * g[lane + 128] + b[lane + 128];
}

// ---------------- Generic GEMM: C = A(MxK) * W(NxK)^T + bias, epilogues -----
// EPI 0: plain store    1: exact GELU then store
// EPI 2: window-reverse + roll(+4,+4) scatter + shortcut add (proj)
// EPI 3: out += val (fc2, accumulate into residual already in out)
#define BM 64
#define BN 64
#define BK 16

template<int EPI>
__global__ __launch_bounds__(256) void gemm_bt(
    const float* __restrict__ A, const float* __restrict__ W,
    const float* __restrict__ bias, float* __restrict__ out,
    const float* __restrict__ xin, int M, int N, int K)
{
    __shared__ float As[BK][BM + 4];
    __shared__ float Ws[BK][BN + 4];
    const int tid = threadIdx.x;
    const int tx = tid & 15, ty = tid >> 4;
    const int lr = tid >> 2;            // 0..63: tile row
    const int lk = (tid & 3) << 2;      // 0,4,8,12: k offset
    const float* Ab = A + (size_t)(blockIdx.y * BM + lr) * K + lk;
    const float* Wb = W + (size_t)(blockIdx.x * BN + lr) * K + lk;
    float acc[4][4] = {};
    for (int k0 = 0; k0 < K; k0 += BK) {
        float4 av = *(const float4*)(Ab + k0);
        float4 wv = *(const float4*)(Wb + k0);
        __syncthreads();
        As[lk + 0][lr] = av.x; As[lk + 1][lr] = av.y;
        As[lk + 2][lr] = av.z; As[lk + 3][lr] = av.w;
        Ws[lk + 0][lr] = wv.x; Ws[lk + 1][lr] = wv.y;
        Ws[lk + 2][lr] = wv.z; Ws[lk + 3][lr] = wv.w;
        __syncthreads();
        #pragma unroll
        for (int kk = 0; kk < BK; ++kk) {
            float4 a = *(const float4*)&As[kk][ty << 2];
            float4 w = *(const float4*)&Ws[kk][tx << 2];
            float ar[4] = {a.x, a.y, a.z, a.w};
            float wr[4] = {w.x, w.y, w.z, w.w};
            #pragma unroll
            for (int i = 0; i < 4; ++i)
                #pragma unroll
                for (int j = 0; j < 4; ++j)
                    acc[i][j] = fmaf(ar[i], wr[j], acc[i][j]);
        }
    }
    #pragma unroll
    for (int i = 0; i < 4; ++i) {
        int r = blockIdx.y * BM + (ty << 2) + i;
        #pragma unroll
        for (int j = 0; j < 4; ++j) {
            int c = blockIdx.x * BN + (tx << 2) + j;
            float val = acc[i][j] + bias[c];
            if (EPI == 0) {
                out[(size_t)r * N + c] = val;
            } else if (EPI == 1) {
                out[(size_t)r * N + c] = val * 0.5f * (1.0f + erff(val * 0.70710678118654752f));
            } else if (EPI == 2) {
                int b_ = r / NWIN, n = r - b_ * NWIN;
                int b = b_ >> 6, hb = (b_ >> 3) & 7, wb = b_ & 7;
                int t = n >> 6, hi = (n >> 3) & 7, wj = n & 7;
                int hs = (hb * 8 + hi + 4) & 63;
                int wsrc = (wb * 8 + wj + 4) & 63;
                size_t dst = ((size_t)b * LTOK + t * 4096 + hs * 64 + wsrc) * DIM + c;
                out[dst] = xin[dst] + val;
            } else {
                out[(size_t)r * N + c] += val;
            }
        }
    }
}

// ---------------- Windowed attention: block = (window b_, head), 320 threads -
// Thread n owns query row n; K/V staged in LDS in two 160-row chunks;
// online softmax; rel-pos bias via collapsed index; mask from region ids.
__global__ __launch_bounds__(320) void attn_kernel(
    const float* __restrict__ qkv, const float* __restrict__ table,
    float* __restrict__ attout)
{
    const int head = blockIdx.x % HEADS;
    const int b_   = blockIdx.x / HEADS;
    const int b = b_ >> 6, hb = (b_ >> 3) & 7, wb = b_ & 7;
    const int n = threadIdx.x;

    __shared__ float kbuf[160][HD];
    __shared__ float vbuf[160][HD];
    __shared__ float tbl[192];
    __shared__ int offm[NWIN];
    __shared__ unsigned char regm[NWIN];

    const int t1 = n >> 6, r1 = (n >> 3) & 7, c1 = n & 7;
    const int h1 = hb * 8 + r1, w1 = wb * 8 + c1;
    const int l1 = t1 * 4096 + ((h1 + 4) & 63) * 64 + ((w1 + 4) & 63);
    const float* myrow = qkv + ((size_t)b * LTOK + l1) * (3 * DIM) + head * HD;

    float q[HD];
    #pragma unroll
    for (int i = 0; i < 8; ++i) {
        float4 qq = *(const float4*)(myrow + 4 * i);
        q[4*i+0] = qq.x * QSCALE; q[4*i+1] = qq.y * QSCALE;
        q[4*i+2] = qq.z * QSCALE; q[4*i+3] = qq.w * QSCALE;
    }
    // per-token metadata (token n viewed as a key): collapsed rel-pos offset
    offm[n] = (7 - t1) * 15 + 7 - r1 - c1;
    int rh = h1 < 56 ? 0 : (h1 < 60 ? 1 : 2);
    int rw = w1 < 56 ? 0 : (w1 < 60 ? 1 : 2);
    const int myreg = rh * 3 + rw;
    regm[n] = (unsigned char)myreg;
    if (n < 187) tbl[n] = table[n * HEADS + head];   // max idx = 186
    const int base_n = t1 * 15 + r1 + c1;

    float mx = -1e30f, ssum = 0.0f;
    float acc[HD] = {};

    for (int chunk = 0; chunk < 2; ++chunk) {
        __syncthreads();   // also covers tbl/offm/regm on first pass
        {
            int half = (n >= 160) ? 1 : 0;
            int mloc = n - half * 160;
            int m = chunk * 160 + mloc;
            int tm = m >> 6, rm = (m >> 3) & 7, cm = m & 7;
            int lm = tm * 4096 + ((hb * 8 + rm + 4) & 63) * 64 + ((wb * 8 + cm + 4) & 63);
            const float* src = qkv + ((size_t)b * LTOK + lm) * (3 * DIM)
                               + (half ? 2 * DIM : DIM) + head * HD;
            float* dstp = half ? vbuf[mloc] : kbuf[mloc];
            #pragma unroll
            for (int i = 0; i < 8; ++i)
                ((float4*)dstp)[i] = *(const float4*)(src + 4 * i);
        }
        __syncthreads();
        #pragma unroll 1
        for (int mm = 0; mm < 160; ++mm) {
            int m = chunk * 160 + mm;
            const float* kr = kbuf[mm];
            float s = 0.0f;
            #pragma unroll
            for (int d = 0; d < HD; ++d) s = fmaf(q[d], kr[d], s);
            s += tbl[base_n + offm[m]];
            if (regm[m] != myreg) s -= 100.0f;
            if (s > mx) {
                float rsc = __expf(mx - s);
                ssum *= rsc;
                #pragma unroll
                for (int d = 0; d < HD; ++d) acc[d] *= rsc;
                mx = s;
            }
            float e = __expf(s - mx);
            ssum += e;
            const float* vr = vbuf[mm];
            #pragma unroll
            for (int d = 0; d < HD; ++d) acc[d] = fmaf(e, vr[d], acc[d]);
        }
    }
    float inv = 1.0f / ssum;
    float* orow = attout + ((size_t)b_ * NWIN + n) * DIM + head * HD;
    #pragma unroll
    for (int i = 0; i < 8; ++i) {
        float4 o = { acc[4*i] * inv, acc[4*i+1] * inv, acc[4*i+2] * inv, acc[4*i+3] * inv };
        *(float4*)(orow + 4 * i) = o;
    }
}

// ---------------------------------------------------------------------------
extern "C" void kernel_launch(void* const* d_in, const int* in_sizes, int n_in,
                              void* d_out, int out_size, void* d_ws, size_t ws_size,
                              hipStream_t stream)
{
    (void)in_sizes; (void)n_in; (void)out_size; (void)ws_size;
    const float* x      = (const float*)d_in[0];
    const float* ln1_g  = (const float*)d_in[1];
    const float* ln1_b  = (const float*)d_in[2];
    const float* qkv_w  = (const float*)d_in[3];
    const float* qkv_b  = (const float*)d_in[4];
    const float* table  = (const float*)d_in[5];
    const float* proj_w = (const float*)d_in[6];
    const float* proj_b = (const float*)d_in[7];
    const float* ln2_g  = (const float*)d_in[8];
    const float* ln2_b  = (const float*)d_in[9];
    const float* fc1_w  = (const float*)d_in[10];
    const float* fc1_b  = (const float*)d_in[11];
    const float* fc2_w  = (const float*)d_in[12];
    const float* fc2_b  = (const float*)d_in[13];
    float* out = (float*)d_out;
    float* ws  = (float*)d_ws;

    // ws layout (floats): h/h2 [M*192] | qkv [M*576] | attout [M*192]
    // fc1out [M*768] overlays qkv+attout (both dead by then). Total 40960*960*4 B.
    float* h_buf   = ws;
    float* qkv_buf = ws + (size_t)MROWS * DIM;
    float* att_buf = ws + (size_t)MROWS * DIM + (size_t)MROWS * 3 * DIM;
    float* fc1_buf = qkv_buf;

    // LN1 -> h
    ln_kernel<<<MROWS / 4, 256, 0, stream>>>(x, ln1_g, ln1_b, h_buf);
    // QKV: (M,192)@(576,192)^T
    gemm_bt<0><<<dim3(3 * DIM / BN, MROWS / BM), 256, 0, stream>>>(
        h_buf, qkv_w, qkv_b, qkv_buf, nullptr, MROWS, 3 * DIM, DIM);
    // Attention per (window, head)
    attn_kernel<<<128 * HEADS, 320, 0, stream>>>(qkv_buf, table, att_buf);
    // Proj + window-reverse + roll + shortcut -> out
    gemm_bt<2><<<dim3(DIM / BN, MROWS / BM), 256, 0, stream>>>(
        att_buf, proj_w, proj_b, out, x, MROWS, DIM, DIM);
    // LN2 -> h
    ln_kernel<<<MROWS / 4, 256, 0, stream>>>(out, ln2_g, ln2_b, h_buf);
    // FC1 + GELU
    gemm_bt<1><<<dim3(4 * DIM / BN, MROWS / BM), 256, 0, stream>>>(
        h_buf, fc1_w, fc1_b, fc1_buf, nullptr, MROWS, 4 * DIM, DIM);
    // FC2, accumulate into residual
    gemm_bt<3><<<dim3(DIM / BN, MROWS / BM), 256, 0, stream>>>(
        fc1_buf, fc2_w, fc2_b, out, nullptr, MROWS, DIM, 4 * DIM);
}